// Round 3
// baseline (580.545 us; speedup 1.0000x reference)
//
#include <hip/hip_runtime.h>

// BiLSTM fused kernel for MI355X (gfx950) — round 3.
// One 64-lane wave per sequence (block=64, grid=4096). Lane j owns gate col j.
// Recurrent matvec via DPP row_ror (intrinsics, not asm -> compiler-managed
// registers, DPP-combine eligible). x_t loads are wave-uniform (b=blockIdx.x)
// -> scalar loads into SGPRs, prefetched 2 steps ahead (even/odd buffers).

__device__ __forceinline__ float tanh_fast(float x) {
    float e = __expf(-2.f * x);
    return __fdividef(2.f, 1.f + e) - 1.f;
}

// rotate v right by S within each row of 16 lanes (DPP row_ror:S)
#define ROT(v, S) __int_as_float(__builtin_amdgcn_mov_dpp(__float_as_int(v), 0x120 | (S), 0xf, 0xf, false))

// 5 rotated fmas per rotation distance S: 4 xh row-copies + 1 h (within-row).
#define FMAC5(S)                                  \
  u0 = fmaf(ROT(c0, S), wfxp[S], u0);             \
  u1 = fmaf(ROT(c1, S), wfxp[16 + S], u1);        \
  u2 = fmaf(ROT(c2, S), wfxp[32 + S], u2);        \
  u3 = fmaf(ROT(c3, S), wfxp[48 + S], u3);        \
  v0 = fmaf(ROT(hh, S), wfhp[S], v0);

// one LSTM timestep consuming x from buffer XB (20 floats, ideally SGPRs)
#define STEP(XB)                                                        \
  {                                                                     \
    float a0 = b0j, a1 = 0.f, a2 = 0.f, a3 = 0.f;                       \
    _Pragma("unroll")                                                   \
    for (int i = 0; i < 5; ++i) {                                       \
      a0 = fmaf(XB[4 * i + 0], w0r[4 * i + 0], a0);                     \
      a1 = fmaf(XB[4 * i + 1], w0r[4 * i + 1], a1);                     \
      a2 = fmaf(XB[4 * i + 2], w0r[4 * i + 2], a2);                     \
      a3 = fmaf(XB[4 * i + 3], w0r[4 * i + 3], a3);                     \
    }                                                                   \
    float xh = fmaxf((a0 + a1) + (a2 + a3), 0.f);                       \
    float c0 = xh;                                                      \
    float c1 = __shfl_xor(xh, 16);                                      \
    float c2 = __shfl_xor(xh, 32);                                      \
    float c3 = __shfl_xor(xh, 48);                                      \
    float u0 = fmaf(c0, wfxp[0], bfj);                                  \
    float u1 = c1 * wfxp[16];                                           \
    float u2 = c2 * wfxp[32];                                           \
    float u3 = c3 * wfxp[48];                                           \
    float v0 = hh * wfhp[0];                                            \
    FMAC5(1)  FMAC5(2)  FMAC5(3)  FMAC5(4)  FMAC5(5)                    \
    FMAC5(6)  FMAC5(7)  FMAC5(8)  FMAC5(9)  FMAC5(10)                   \
    FMAC5(11) FMAC5(12) FMAC5(13) FMAC5(14) FMAC5(15)                   \
    float gated = ((u0 + u1) + (u2 + u3)) + v0;                         \
    float e = __expf(gmul * (gated + gbias));                           \
    float y = __fdividef(1.f, 1.f + e);                                 \
    float a = fmaf(y, amul, aadd);                                      \
    float d1 = __shfl_xor(a, 16);                                       \
    float d2 = __shfl_xor(a, 32);                                       \
    float d3 = __shfl_xor(a, 48);                                       \
    float lo  = b0sel ? d1 : a;                                         \
    float hi  = b0sel ? d3 : d2;                                        \
    float lo1 = b0sel ? a  : d1;                                        \
    float hi1 = b0sel ? d2 : d3;                                        \
    float ai = b1sel ? hi  : lo;                                        \
    float ag = b1sel ? hi1 : lo1;                                       \
    float af = b1sel ? lo  : hi;                                        \
    float ao = b1sel ? lo1 : hi1;                                       \
    c  = fmaf(af, c, ai * ag);                                          \
    hh = ao * tanh_fast(c);                                             \
    xh_last = xh;                                                       \
  }

__global__ __launch_bounds__(64, 3)
void bilstm_fused(const float* __restrict__ x,
                  const float* __restrict__ W0, const float* __restrict__ b0,
                  const float* __restrict__ Wf, const float* __restrict__ bf,
                  const float* __restrict__ Wb, const float* __restrict__ bb,
                  const float* __restrict__ W1, const float* __restrict__ b1,
                  const float* __restrict__ W2, const float* __restrict__ b2,
                  const float* __restrict__ W3, const float* __restrict__ b3,
                  float* __restrict__ out)
{
    __shared__ __align__(16) float xh_sh[64];  // epilogue only
    __shared__ __align__(16) float h_sh[48];   // [0:16) hf, [16:32) hb, [32:48) l2

    const int j  = threadIdx.x;    // 0..63
    const int b  = blockIdx.x;     // wave-uniform sequence index
    const int r  = j >> 4;         // quad == row-of-16 == gate index
    const int jq = j & 15;

    // runtime probe of row_ror source direction (same as passing R2)
    int rot1 = __builtin_amdgcn_mov_dpp(j, 0x121, 0xf, 0xf, false);
    const bool plus = ((rot1 & 15) == ((jq + 1) & 15));

    // register-resident weights, permuted to the rotation schedule (as R2)
    float w0r[20], wfxp[64], wfhp[16];
#pragma unroll
    for (int k = 0; k < 20; ++k) w0r[k] = W0[k * 64 + j];
#pragma unroll
    for (int s = 0; s < 16; ++s) {
        const int srcq = plus ? ((jq + s) & 15) : ((jq + 16 - s) & 15);
        wfhp[s] = Wf[(64 + srcq) * 64 + j];
#pragma unroll
        for (int m = 0; m < 4; ++m)
            wfxp[m * 16 + s] = Wf[(16 * (r ^ m) + srcq) * 64 + j];
    }
    const float b0j = b0[j];
    const float bfj = bf[j];

    const float gmul  = (r == 1) ? -2.f : -1.f;
    const float gbias = (r == 2) ? 1.f : 0.f;
    const float amul  = (r == 1) ? 2.f : 1.f;
    const float aadd  = (r == 1) ? -1.f : 0.f;
    const bool  b0sel = (r & 1) != 0;
    const bool  b1sel = (r & 2) != 0;

    float c = 0.f, hh = 0.f, xh_last = 0.f;
    const float* xb = x + (size_t)b * (256 * 20);  // uniform -> scalar loads

    // prefetch buffers: even / odd timestep (distance-2 pipeline)
    float sxE[20], sxO[20];
#pragma unroll
    for (int i = 0; i < 20; ++i) { sxE[i] = xb[i]; sxO[i] = xb[20 + i]; }

#pragma unroll 1
    for (int t = 0; t < 256; t += 2) {
        STEP(sxE)
        {
            int t2 = t + 2; t2 = (t2 > 255) ? 254 : t2;   // dummy addr on tail
            const float* p = xb + t2 * 20;
#pragma unroll
            for (int i = 0; i < 20; ++i) sxE[i] = p[i];
        }
        STEP(sxO)
        {
            int t3 = t + 3; t3 = (t3 > 255) ? 255 : t3;
            const float* p = xb + t3 * 20;
#pragma unroll
            for (int i = 0; i < 20; ++i) sxO[i] = p[i];
        }
    }

    // ================= one-time epilogue =================
    xh_sh[j] = xh_last;
    if (j < 16) h_sh[j] = hh;
    __builtin_amdgcn_wave_barrier();

    // backward LSTM output at t=T-1: one step from zero state on xh_{T-1}
    {
        float u0 = bb[j], u1 = 0.f, u2 = 0.f, u3 = 0.f;
        const float4* xs = (const float4*)xh_sh;
#pragma unroll
        for (int k4 = 0; k4 < 16; ++k4) {
            float4 v = xs[k4];
            u0 = fmaf(v.x, Wb[(4 * k4 + 0) * 64 + j], u0);
            u1 = fmaf(v.y, Wb[(4 * k4 + 1) * 64 + j], u1);
            u2 = fmaf(v.z, Wb[(4 * k4 + 2) * 64 + j], u2);
            u3 = fmaf(v.w, Wb[(4 * k4 + 3) * 64 + j], u3);
        }
        float gated = (u0 + u1) + (u2 + u3);
        float e = __expf(gmul * gated);   // f-gate irrelevant (c_prev=0)
        float y = __fdividef(1.f, 1.f + e);
        float a = fmaf(y, amul, aadd);
        float ai = __shfl(a, jq, 64);
        float ag = __shfl(a, jq + 16, 64);
        float ao = __shfl(a, jq + 48, 64);
        float cb = ai * ag;
        float hb = ao * tanh_fast(cb);
        __builtin_amdgcn_wave_barrier();
        if (j < 16) h_sh[16 + j] = hb;
        __builtin_amdgcn_wave_barrier();
    }

    // head MLP: l1 = relu([hf,hb] @ W1 + b1)
    {
        float u0 = b1[j], u1 = 0.f, u2 = 0.f, u3 = 0.f;
        const float4* hs = (const float4*)h_sh;
#pragma unroll
        for (int k4 = 0; k4 < 8; ++k4) {
            float4 v = hs[k4];
            u0 = fmaf(v.x, W1[(4 * k4 + 0) * 64 + j], u0);
            u1 = fmaf(v.y, W1[(4 * k4 + 1) * 64 + j], u1);
            u2 = fmaf(v.z, W1[(4 * k4 + 2) * 64 + j], u2);
            u3 = fmaf(v.w, W1[(4 * k4 + 3) * 64 + j], u3);
        }
        float l1 = fmaxf((u0 + u1) + (u2 + u3), 0.f);
        __builtin_amdgcn_wave_barrier();
        xh_sh[j] = l1;
        __builtin_amdgcn_wave_barrier();

        if (j < 16) {
            float v0 = b2[j], v1 = 0.f, v2 = 0.f, v3 = 0.f;
            const float4* ls = (const float4*)xh_sh;
#pragma unroll
            for (int k4 = 0; k4 < 16; ++k4) {
                float4 v = ls[k4];
                v0 = fmaf(v.x, W2[(4 * k4 + 0) * 16 + j], v0);
                v1 = fmaf(v.y, W2[(4 * k4 + 1) * 16 + j], v1);
                v2 = fmaf(v.z, W2[(4 * k4 + 2) * 16 + j], v2);
                v3 = fmaf(v.w, W2[(4 * k4 + 3) * 16 + j], v3);
            }
            h_sh[32 + j] = fmaxf((v0 + v1) + (v2 + v3), 0.f);
        }
        __builtin_amdgcn_wave_barrier();

        if (j < 2) {
            float o = b3[j];
#pragma unroll
            for (int k = 0; k < 16; ++k)
                o = fmaf(h_sh[32 + k], W3[k * 2 + j], o);
            out[b * 2 + j] = o;
        }
    }
}

extern "C" void kernel_launch(void* const* d_in, const int* in_sizes, int n_in,
                              void* d_out, int out_size, void* d_ws, size_t ws_size,
                              hipStream_t stream) {
    const float* x  = (const float*)d_in[0];
    const float* W0 = (const float*)d_in[1];
    const float* b0 = (const float*)d_in[2];
    const float* Wf = (const float*)d_in[3];
    const float* bf = (const float*)d_in[4];
    const float* Wb = (const float*)d_in[5];
    const float* bb = (const float*)d_in[6];
    const float* W1 = (const float*)d_in[7];
    const float* b1 = (const float*)d_in[8];
    const float* W2 = (const float*)d_in[9];
    const float* b2 = (const float*)d_in[10];
    const float* W3 = (const float*)d_in[11];
    const float* b3 = (const float*)d_in[12];
    float* outp = (float*)d_out;

    hipLaunchKernelGGL(bilstm_fused, dim3(4096), dim3(64), 0, stream,
                       x, W0, b0, Wf, bf, Wb, bb, W1, b1, W2, b2, W3, b3, outp);
}

// Round 4
// 312.323 us; speedup vs baseline: 1.8588x; 1.8588x over previous
//
#include <hip/hip_runtime.h>

// BiLSTM fused kernel for MI355X (gfx950) — round 4: MFMA for the non-recurrent GEMMs.
// B=4096, T=256, D=20, E=64, H=16, 4H=64. One wave per sequence (block=64, grid=4096).
// Per 16-step chunk: xh = relu(x@W0+b0) via split-bf16 MFMA (3-product),
// LDS transpose C->A layout, gpre = xh@Wfx + bf via split-bf16 MFMA, gpre -> LDS.
// Serial loop per step: gpre ds_read + 16 DPP h-fmacs + gate math (R2/R3-verified).
// bwd LSTM output at t=T-1 is one step from zero state (reverse-scan semantics).

typedef __attribute__((ext_vector_type(8))) short short8;
typedef __attribute__((ext_vector_type(4))) float floatx4;

union F8 { uint32_t u[4]; short8 v; };

#define LDW 66  // LDS row stride (dwords): 66 ≡ 2 mod 32 -> ≤2-way bank aliasing (free)

__device__ __forceinline__ float tanh_fast(float x) {
    float e = __expf(-2.f * x);
    return __fdividef(2.f, 1.f + e) - 1.f;
}

// rotate v right by S within each row of 16 lanes (DPP row_ror:S)
#define ROT(v, S) __int_as_float(__builtin_amdgcn_mov_dpp(__float_as_int(v), 0x120 | (S), 0xf, 0xf, false))

// split f[0..7] (fp32) into truncated-bf16 hi and residual-bf16 lo fragments
__device__ __forceinline__ void split_pack(const float* f, uint32_t* hi, uint32_t* lo) {
#pragma unroll
    for (int i = 0; i < 4; ++i) {
        uint32_t u0 = __float_as_uint(f[2 * i]), u1 = __float_as_uint(f[2 * i + 1]);
        hi[i] = (u0 >> 16) | (u1 & 0xFFFF0000u);
        float r0 = f[2 * i]     - __uint_as_float(u0 & 0xFFFF0000u);
        float r1 = f[2 * i + 1] - __uint_as_float(u1 & 0xFFFF0000u);
        uint32_t v0 = __float_as_uint(r0), v1 = __float_as_uint(r1);
        lo[i] = (v0 >> 16) | (v1 & 0xFFFF0000u);
    }
}

__global__ __launch_bounds__(64, 2)
void bilstm_fused(const float* __restrict__ x,
                  const float* __restrict__ W0, const float* __restrict__ b0,
                  const float* __restrict__ Wf, const float* __restrict__ bf,
                  const float* __restrict__ Wb, const float* __restrict__ bb,
                  const float* __restrict__ W1, const float* __restrict__ b1,
                  const float* __restrict__ W2, const float* __restrict__ b2,
                  const float* __restrict__ W3, const float* __restrict__ b3,
                  float* __restrict__ out)
{
    __shared__ __align__(16) float lds_xh[16 * LDW];  // xh[tau][e], row-stride LDW
    __shared__ __align__(16) float lds_g [16 * LDW];  // gpre[tau][n] (incl bf bias)
    __shared__ __align__(16) float h_sh[48];          // [0:16) hf, [16:32) hb, [32:48) l2

    const int j    = threadIdx.x;   // 0..63
    const int b    = blockIdx.x;    // sequence index
    const int nl   = j & 15;
    const int quad = j >> 4;

    // ---- runtime probe of row_ror source direction (R2/R3-verified)
    int rot1 = __builtin_amdgcn_mov_dpp(j, 0x121, 0xf, 0xf, false);
    const bool plus = ((rot1 & 15) == ((nl + 1) & 15));

    // ---- serial h-matvec weights, permuted to the rotation schedule (R2/R3-verified)
    float wfhp[16];
#pragma unroll
    for (int s = 0; s < 16; ++s) {
        const int srcq = plus ? ((nl + s) & 15) : ((nl + 16 - s) & 15);
        wfhp[s] = Wf[(64 + srcq) * 64 + j];
    }

    // ---- MFMA B fragments (B[k][n]: n = lane&15 (+tile*16), k = quad*8 + e)
    F8 B1h[4], B1l[4];           // W0 (20x64), k>=20 zero-padded
#pragma unroll
    for (int T = 0; T < 4; ++T) {
        float w[8];
#pragma unroll
        for (int e = 0; e < 8; ++e) {
            int k = quad * 8 + e;
            w[e] = (k < 20) ? W0[k * 64 + T * 16 + nl] : 0.f;
        }
        split_pack(w, B1h[T].u, B1l[T].u);
    }
    F8 B2h[4][2], B2l[4][2];     // Wfx = Wf rows 0..63
#pragma unroll
    for (int T = 0; T < 4; ++T)
#pragma unroll
        for (int KH = 0; KH < 2; ++KH) {
            float w[8];
#pragma unroll
            for (int e = 0; e < 8; ++e) {
                int k = KH * 32 + quad * 8 + e;
                w[e] = Wf[k * 64 + T * 16 + nl];
            }
            split_pack(w, B2h[T][KH].u, B2l[T][KH].u);
        }

    float b0v[4], bfv[4];
#pragma unroll
    for (int T = 0; T < 4; ++T) {
        b0v[T] = b0[T * 16 + nl];
        bfv[T] = bf[T * 16 + nl];
    }

    const float gmul  = (quad == 1) ? -2.f : -1.f;
    const float gbias = (quad == 2) ? 1.f : 0.f;
    const float amul  = (quad == 1) ? 2.f : 1.f;
    const float aadd  = (quad == 1) ? -1.f : 0.f;
    const bool  b0sel = (quad & 1) != 0;
    const bool  b1sel = (quad & 2) != 0;

    float c = 0.f, hh = 0.f;
    const float* xb = x + (size_t)b * (256 * 20);

#pragma unroll 1
    for (int ch = 0; ch < 16; ++ch) {
        const int t0 = ch * 16;

        // ---- stage 1: A = x[t0..t0+15][0..31] in A-layout (m=lane&15, k=quad*8+e)
        const float* xrow = xb + (size_t)(t0 + nl) * 20;
        float xk[8];
#pragma unroll
        for (int e = 0; e < 8; ++e) {
            int k = quad * 8 + e;
            xk[e] = (k < 20) ? xrow[k] : 0.f;
        }
        F8 A1h, A1l;
        split_pack(xk, A1h.u, A1l.u);

        floatx4 acc1[4];
#pragma unroll
        for (int T = 0; T < 4; ++T) acc1[T] = (floatx4){b0v[T], b0v[T], b0v[T], b0v[T]};
#pragma unroll
        for (int T = 0; T < 4; ++T) {
            acc1[T] = __builtin_amdgcn_mfma_f32_16x16x32_bf16(A1h.v, B1h[T].v, acc1[T], 0, 0, 0);
            acc1[T] = __builtin_amdgcn_mfma_f32_16x16x32_bf16(A1l.v, B1h[T].v, acc1[T], 0, 0, 0);
            acc1[T] = __builtin_amdgcn_mfma_f32_16x16x32_bf16(A1h.v, B1l[T].v, acc1[T], 0, 0, 0);
        }

        // ---- relu + transpose via LDS: C-layout (m=quad*4+reg, n=T*16+nl) -> [tau][e]
#pragma unroll
        for (int T = 0; T < 4; ++T)
#pragma unroll
            for (int reg = 0; reg < 4; ++reg)
                lds_xh[(quad * 4 + reg) * LDW + T * 16 + nl] = fmaxf(acc1[T][reg], 0.f);
        __builtin_amdgcn_wave_barrier();

        // ---- stage 2 A-frags: A[m=lane&15][k=quad*8+e] from lds_xh
        F8 A2h[2], A2l[2];
#pragma unroll
        for (int KH = 0; KH < 2; ++KH) {
            float xe[8];
#pragma unroll
            for (int e = 0; e < 8; ++e)
                xe[e] = lds_xh[nl * LDW + KH * 32 + quad * 8 + e];
            split_pack(xe, A2h[KH].u, A2l[KH].u);
        }

        floatx4 acc2[4];
#pragma unroll
        for (int T = 0; T < 4; ++T) acc2[T] = (floatx4){bfv[T], bfv[T], bfv[T], bfv[T]};
#pragma unroll
        for (int T = 0; T < 4; ++T)
#pragma unroll
            for (int KH = 0; KH < 2; ++KH) {
                acc2[T] = __builtin_amdgcn_mfma_f32_16x16x32_bf16(A2h[KH].v, B2h[T][KH].v, acc2[T], 0, 0, 0);
                acc2[T] = __builtin_amdgcn_mfma_f32_16x16x32_bf16(A2l[KH].v, B2h[T][KH].v, acc2[T], 0, 0, 0);
                acc2[T] = __builtin_amdgcn_mfma_f32_16x16x32_bf16(A2h[KH].v, B2l[T][KH].v, acc2[T], 0, 0, 0);
            }

        // ---- gpre -> LDS [tau][n]
#pragma unroll
        for (int T = 0; T < 4; ++T)
#pragma unroll
            for (int reg = 0; reg < 4; ++reg)
                lds_g[(quad * 4 + reg) * LDW + T * 16 + nl] = acc2[T][reg];
        __builtin_amdgcn_wave_barrier();

        // ---- 16 serial LSTM steps (gate math verbatim from R2/R3-verified STEP)
        float gcur = lds_g[j];   // tau = 0
#pragma unroll
        for (int tau = 0; tau < 16; ++tau) {
            float gnext = lds_g[((tau < 15) ? (tau + 1) : 15) * LDW + j];

            // h @ Wfh[:,j] : 16 DPP fmacs in 4 chains
            float v0 = hh * wfhp[0];
            float v1 = ROT(hh, 1) * wfhp[1];
            float v2 = ROT(hh, 2) * wfhp[2];
            float v3 = ROT(hh, 3) * wfhp[3];
            v0 = fmaf(ROT(hh, 4),  wfhp[4],  v0);
            v1 = fmaf(ROT(hh, 5),  wfhp[5],  v1);
            v2 = fmaf(ROT(hh, 6),  wfhp[6],  v2);
            v3 = fmaf(ROT(hh, 7),  wfhp[7],  v3);
            v0 = fmaf(ROT(hh, 8),  wfhp[8],  v0);
            v1 = fmaf(ROT(hh, 9),  wfhp[9],  v1);
            v2 = fmaf(ROT(hh, 10), wfhp[10], v2);
            v3 = fmaf(ROT(hh, 11), wfhp[11], v3);
            v0 = fmaf(ROT(hh, 12), wfhp[12], v0);
            v1 = fmaf(ROT(hh, 13), wfhp[13], v1);
            v2 = fmaf(ROT(hh, 14), wfhp[14], v2);
            v3 = fmaf(ROT(hh, 15), wfhp[15], v3);
            float gated = gcur + ((v0 + v1) + (v2 + v3));

            float e = __expf(gmul * (gated + gbias));
            float y = __fdividef(1.f, 1.f + e);
            float a = fmaf(y, amul, aadd);

            float d1 = __shfl_xor(a, 16);
            float d2 = __shfl_xor(a, 32);
            float d3 = __shfl_xor(a, 48);
            float lo  = b0sel ? d1 : a;
            float hi  = b0sel ? d3 : d2;
            float lo1 = b0sel ? a  : d1;
            float hi1 = b0sel ? d2 : d3;
            float ai = b1sel ? hi  : lo;
            float ag = b1sel ? hi1 : lo1;
            float af = b1sel ? lo  : hi;
            float ao = b1sel ? lo1 : hi1;

            c  = fmaf(af, c, ai * ag);
            hh = ao * tanh_fast(c);
            gcur = gnext;
        }
    }

    // ================= one-time epilogue =================
    if (j < 16) h_sh[j] = hh;
    __builtin_amdgcn_wave_barrier();

    // backward LSTM output at t=T-1: one step from zero state on xh_{T-1}
    // xh[255][k] = lds_xh[15*LDW + k] (last chunk's transpose buffer, row 15)
    {
        float u0 = bb[j], u1 = 0.f, u2 = 0.f, u3 = 0.f;
        const float* xr = &lds_xh[15 * LDW];
#pragma unroll
        for (int k4 = 0; k4 < 16; ++k4) {
            float q0 = xr[4 * k4 + 0], q1 = xr[4 * k4 + 1];
            float q2 = xr[4 * k4 + 2], q3 = xr[4 * k4 + 3];
            u0 = fmaf(q0, Wb[(4 * k4 + 0) * 64 + j], u0);
            u1 = fmaf(q1, Wb[(4 * k4 + 1) * 64 + j], u1);
            u2 = fmaf(q2, Wb[(4 * k4 + 2) * 64 + j], u2);
            u3 = fmaf(q3, Wb[(4 * k4 + 3) * 64 + j], u3);
        }
        float gated = (u0 + u1) + (u2 + u3);
        float e = __expf(gmul * gated);   // f-gate irrelevant (c_prev=0)
        float y = __fdividef(1.f, 1.f + e);
        float a = fmaf(y, amul, aadd);
        float ai = __shfl(a, nl, 64);
        float ag = __shfl(a, nl + 16, 64);
        float ao = __shfl(a, nl + 48, 64);
        float cb = ai * ag;
        float hb = ao * tanh_fast(cb);
        __builtin_amdgcn_wave_barrier();
        if (j < 16) h_sh[16 + j] = hb;
        __builtin_amdgcn_wave_barrier();
    }

    // head MLP: l1 = relu([hf,hb] @ W1 + b1)
    {
        float u0 = b1[j], u1 = 0.f, u2 = 0.f, u3 = 0.f;
        const float4* hs = (const float4*)h_sh;
#pragma unroll
        for (int k4 = 0; k4 < 8; ++k4) {
            float4 v = hs[k4];
            u0 = fmaf(v.x, W1[(4 * k4 + 0) * 64 + j], u0);
            u1 = fmaf(v.y, W1[(4 * k4 + 1) * 64 + j], u1);
            u2 = fmaf(v.z, W1[(4 * k4 + 2) * 64 + j], u2);
            u3 = fmaf(v.w, W1[(4 * k4 + 3) * 64 + j], u3);
        }
        float l1 = fmaxf((u0 + u1) + (u2 + u3), 0.f);
        __builtin_amdgcn_wave_barrier();
        lds_g[j] = l1;                    // reuse as l1 broadcast buffer
        __builtin_amdgcn_wave_barrier();

        if (j < 16) {
            float v0 = b2[j], v1 = 0.f, v2 = 0.f, v3 = 0.f;
            const float4* ls = (const float4*)lds_g;
#pragma unroll
            for (int k4 = 0; k4 < 16; ++k4) {
                float4 v = ls[k4];
                v0 = fmaf(v.x, W2[(4 * k4 + 0) * 16 + j], v0);
                v1 = fmaf(v.y, W2[(4 * k4 + 1) * 16 + j], v1);
                v2 = fmaf(v.z, W2[(4 * k4 + 2) * 16 + j], v2);
                v3 = fmaf(v.w, W2[(4 * k4 + 3) * 16 + j], v3);
            }
            h_sh[32 + j] = fmaxf((v0 + v1) + (v2 + v3), 0.f);
        }
        __builtin_amdgcn_wave_barrier();

        if (j < 2) {
            float o = b3[j];
#pragma unroll
            for (int k = 0; k < 16; ++k)
                o = fmaf(h_sh[32 + k], W3[k * 2 + j], o);
            out[b * 2 + j] = o;
        }
    }
}

extern "C" void kernel_launch(void* const* d_in, const int* in_sizes, int n_in,
                              void* d_out, int out_size, void* d_ws, size_t ws_size,
                              hipStream_t stream) {
    const float* x  = (const float*)d_in[0];
    const float* W0 = (const float*)d_in[1];
    const float* b0 = (const float*)d_in[2];
    const float* Wf = (const float*)d_in[3];
    const float* bf = (const float*)d_in[4];
    const float* Wb = (const float*)d_in[5];
    const float* bb = (const float*)d_in[6];
    const float* W1 = (const float*)d_in[7];
    const float* b1 = (const float*)d_in[8];
    const float* W2 = (const float*)d_in[9];
    const float* b2 = (const float*)d_in[10];
    const float* W3 = (const float*)d_in[11];
    const float* b3 = (const float*)d_in[12];
    float* outp = (float*)d_out;

    hipLaunchKernelGGL(bilstm_fused, dim3(4096), dim3(64), 0, stream,
                       x, W0, b0, Wf, bf, Wb, bb, W1, b1, W2, b2, W3, b3, outp);
}